// Round 7
// baseline (5367.986 us; speedup 1.0000x reference)
//
#include <hip/hip_runtime.h>
#include <hip/hip_bf16.h>
#include <cstdint>
#include <cstddef>

typedef unsigned short u16;
typedef unsigned int u32;
typedef __attribute__((ext_vector_type(8))) short short8;   // 8 x bf16 (MFMA A/B frag)
typedef __attribute__((ext_vector_type(4))) float f32x4;    // MFMA C/D frag
typedef __attribute__((ext_vector_type(4))) float f4v;
typedef __attribute__((ext_vector_type(4))) u16 u16x4;

// B=64, T=128, I=512, H=256 (4H=1024), O=512
__device__ __forceinline__ u16 f2bf(float f) {
  u32 u = __float_as_uint(f);
  u32 r = (u + 0x7fffu + ((u >> 16) & 1u)) >> 16;   // RNE
  return (u16)r;
}
__device__ __forceinline__ float bf2f(u16 v) { return __uint_as_float(((u32)v) << 16); }
__device__ __forceinline__ float sigm(float x) { return 1.f / (1.f + __expf(-x)); }
__device__ __forceinline__ float tanh_(float x) {
  x = fminf(fmaxf(x, -30.f), 30.f);
  float e = __expf(-2.f * x);
  return (1.f - e) / (1.f + e);
}

#define SWZ(row, kb) ((kb) ^ (((row) & 7) << 4))

// ---------- f32 -> bf16 convert ----------
__global__ void cvt_bf16_kernel(const float* __restrict__ src, u16* __restrict__ dst, int n4) {
  int i = blockIdx.x * blockDim.x + threadIdx.x;
  int stride = gridDim.x * blockDim.x;
  for (; i < n4; i += stride) {
    f4v v = *(const f4v*)(src + (size_t)i * 4);
    u16x4 o;
    o.x = f2bf(v.x); o.y = f2bf(v.y); o.z = f2bf(v.z); o.w = f2bf(v.w);
    *(u16x4*)(dst + (size_t)i * 4) = o;
  }
}

// ---------- split input: x[8192,512] f32 -> XH[8192,1536] = [x_hi | x_lo | x_hi] ----------
__global__ void split_input_kernel(const float* __restrict__ src, u16* __restrict__ dst, int total) {
  int idx = blockIdx.x * blockDim.x + threadIdx.x;
  int stride = gridDim.x * blockDim.x;
  for (; idx < total; idx += stride) {
    int r = idx >> 9, c = idx & 511;
    float x = src[idx];
    u16 hi = f2bf(x);
    u16 lo = f2bf(x - bf2f(hi));
    u16* d = dst + (size_t)r * 1536;
    d[c] = hi; d[512 + c] = lo; d[1024 + c] = hi;
  }
}
// ---------- split weight: W[1024,512] f32 -> dst rows [W_hi | W_hi | W_lo] ----------
__global__ void split_w_kernel(const float* __restrict__ src, u16* __restrict__ dst) {
  int idx = blockIdx.x * blockDim.x + threadIdx.x;  // 524288 exact
  int r = idx >> 9, c = idx & 511;
  float x = src[idx];
  u16 hi = f2bf(x);
  u16 lo = f2bf(x - bf2f(hi));
  u16* d = dst + (size_t)r * 1536;
  d[c] = hi; d[512 + c] = hi; d[1024 + c] = lo;
}

__global__ void fill_u32_kernel(u32* __restrict__ p, u32 val, int n) {
  int i = blockIdx.x * blockDim.x + threadIdx.x;
  int stride = gridDim.x * blockDim.x;
  for (; i < n; i += stride) p[i] = val;
}

// ---------- bf16 GEMM, split-N epilogue ----------
__global__ __launch_bounds__(256, 1) void gemm_bt_kernel(
    const u16* __restrict__ A, int lda, const u16* __restrict__ W, int ldw,
    const float* __restrict__ b0, const float* __restrict__ b1,
    float* __restrict__ C0, float* __restrict__ C1, int nsplit,
    int M, int K) {
  __shared__ __align__(16) u16 As[128 * 64];
  __shared__ __align__(16) u16 Bs[128 * 64];
  const int m0 = blockIdx.y * 128, n0 = blockIdx.x * 128;
  const int tid = threadIdx.x;
  const int w = tid >> 6, l = tid & 63;
  const int wr = w >> 1, wc = w & 1;
  const int lhi = l >> 4, llo = l & 15;

  f32x4 acc[4][4];
#pragma unroll
  for (int a = 0; a < 4; ++a)
#pragma unroll
    for (int b = 0; b < 4; ++b) acc[a][b] = (f32x4){0.f, 0.f, 0.f, 0.f};

  for (int k0 = 0; k0 < K; k0 += 64) {
    __syncthreads();
#pragma unroll
    for (int it = 0; it < 4; ++it) {
      int off = it * 4096 + tid * 16;
      int row = off >> 7, kb = off & 127;
      short8 va = *(const short8*)((const char*)A + ((size_t)(m0 + row) * lda + k0) * 2 + kb);
      *(short8*)((char*)As + row * 128 + SWZ(row, kb)) = va;
      short8 vb = *(const short8*)((const char*)W + ((size_t)(n0 + row) * ldw + k0) * 2 + kb);
      *(short8*)((char*)Bs + row * 128 + SWZ(row, kb)) = vb;
    }
    __syncthreads();
    short8 af[4][2], bf[4][2];
#pragma unroll
    for (int mt = 0; mt < 4; ++mt)
#pragma unroll
      for (int ks = 0; ks < 2; ++ks) {
        int row = wr * 64 + mt * 16 + llo;
        int kb = ks * 64 + lhi * 16;
        af[mt][ks] = *(const short8*)((const char*)As + row * 128 + SWZ(row, kb));
      }
#pragma unroll
    for (int nt = 0; nt < 4; ++nt)
#pragma unroll
      for (int ks = 0; ks < 2; ++ks) {
        int row = wc * 64 + nt * 16 + llo;
        int kb = ks * 64 + lhi * 16;
        bf[nt][ks] = *(const short8*)((const char*)Bs + row * 128 + SWZ(row, kb));
      }
#pragma unroll
    for (int ks = 0; ks < 2; ++ks)
#pragma unroll
      for (int mt = 0; mt < 4; ++mt)
#pragma unroll
        for (int nt = 0; nt < 4; ++nt)
          acc[mt][nt] = __builtin_amdgcn_mfma_f32_16x16x32_bf16(af[mt][ks], bf[nt][ks], acc[mt][nt], 0, 0, 0);
  }
#pragma unroll
  for (int mt = 0; mt < 4; ++mt)
#pragma unroll
    for (int nt = 0; nt < 4; ++nt) {
      int col = n0 + wc * 64 + nt * 16 + llo;
      const float* bp; float* Cp; int cc;
      if (col < nsplit) { bp = b0; Cp = C0; cc = col; }
      else              { bp = b1; Cp = C1; cc = col - nsplit; }
      float bz = bp[cc];
#pragma unroll
      for (int i = 0; i < 4; ++i) {
        int row = m0 + wr * 64 + mt * 16 + lhi * 4 + i;
        Cp[(size_t)row * nsplit + cc] = acc[mt][nt][i] + bz;
      }
    }
}

// ---------- run-merged LSTM scan ----------
// Block = (dir, run-group, batch-row group). NSLOT run slots x NR rows = NSLOT*NR vrows.
// vrow = slot*NR + row. All runs in the block share xp (read once/step) and W (streamed once/step).
// 8 waves; wave w owns channels {16w..16w+15} u {128+16w..} for all 4 gates (gate-strided N-tiles)
// so the cell update is wave-local. h double-buffered in LDS -> ONE barrier per step.
// Phase 1: grid 64 = dir(2) x grp(2) x rg(16, 4 rows). grp0: runs 0..15 (slot0 of fwd/bwd grp0 =
//   full run -> store HFfull/HBfull); grp1: runs 16..25 (+6 pad). Variants write window maxes
//   to pA (window head in this source) / pB (window tail) non-atomically.
// Phase 2: grid 8 = dir(2) x rg(4, 16 rows); store REC (out pre-offset by dir*256).
// __launch_bounds__(512,1): grid (64) < #CU (256) so >1 block/CU never happens; the 256-VGPR
// budget avoids spilling the ~192 live VGPRs of the inner pass.
template<int NSLOT, int NR, int PHASE>
__global__ __launch_bounds__(512, 1) void scan_kernel(
    const u16* __restrict__ Wf, const u16* __restrict__ Wb,
    const float* __restrict__ xpF, const float* __restrict__ xpB,
    u16* __restrict__ outF, u16* __restrict__ outB,
    u16* __restrict__ pA, u16* __restrict__ pB) {
  constexpr int MT = (NSLOT * NR) / 16;     // M-tiles: 4 (phase1) or 1 (phase2)
  constexpr int NV = NSLOT * NR;            // vrows
  __shared__ __align__(16) u16 hlds[2][NV * 256];

  const int bid = blockIdx.x;
  int dir, grp, rgbase;
  if (PHASE == 1) { dir = bid >> 5; grp = (bid >> 4) & 1; rgbase = (bid & 15) * NR; }
  else            { dir = bid >> 2; grp = 0;              rgbase = (bid & 3) * NR; }
  const bool fwd = (dir == 0);
  const u16* W = fwd ? Wf : Wb;
  const float* xp = fwd ? xpF : xpB;
  u16* out = fwd ? outF : outB;
  const int runbase = grp * 16;

  int t0, nsteps, tstep;
  if (PHASE == 2) {
    tstep = fwd ? 1 : -1; t0 = fwd ? 0 : 127; nsteps = 128;
  } else if (fwd) {
    tstep = 1;  if (grp == 0) { t0 = 0;   nsteps = 128; } else { t0 = 16; nsteps = 112; }
  } else {
    tstep = -1; if (grp == 0) { t0 = 127; nsteps = 128; } else { t0 = 24; nsteps = 25;  }
  }

  const int tid = threadIdx.x;
  const int w = tid >> 6, l = tid & 63;
  const int lhi = l >> 4, llo = l & 15;

  for (int i = tid; i < NV * 256; i += 512) { hlds[0][i] = 0; hlds[1][i] = 0; }
  float cst[2][MT][4];
#pragma unroll
  for (int p = 0; p < 2; ++p)
#pragma unroll
    for (int mt = 0; mt < MT; ++mt)
#pragma unroll
      for (int i = 0; i < 4; ++i) cst[p][mt][i] = 0.f;
  __syncthreads();

  // W per-lane base: row n = g*256 + p*128 + w*16 + llo; byte = n*512 + ks*64 + lhi*16
  const char* Wl = (const char*)W + (size_t)(w * 16 + llo) * 512 + lhi * 16;

  int cur = 0;
  int t = t0, tprev = t0;
  for (int it = 0; it < nsteps; ++it, t += tstep) {
    const u16* hb = hlds[cur];
    u16* hw = hlds[cur ^ 1];

    // ---- window-max of h(tprev) for variant runs (reads hb) ----
    if (PHASE == 1 && it > 0) {
#pragma unroll
      for (int rep = 0; rep < 2; ++rep) {
        int jj = tid + rep * 512;
        if (jj < 768) {
          int slot = jj / 48, rem = jj - slot * 48;
          int row = rem / 12, ws = rem - row * 12;
          int j = runbase + slot;
          if (j >= 1 && j <= 25 && (fwd ? (tprev >= j) : (tprev <= j - 1))) {
            int flatbase = (j - 1) * 512 + (fwd ? 0 : 256);
            int qlo = (flatbase * 5243) >> 17;
            int qhi = ((flatbase + 255) * 5243) >> 17;
            int q = qlo + ws;
            if (q <= qhi) {
              int lo = q * 25 - flatbase;
              int chlo = lo < 0 ? 0 : lo, chhi = lo + 24 > 255 ? 255 : lo + 24;
              int vrow = slot * NR + row;
              float m = -3.4e38f;
              for (int ch = chlo; ch <= chhi; ++ch)
                m = fmaxf(m, bf2f(*(const u16*)((const char*)hb + ((vrow * 512 + ch * 2) ^ ((vrow & 7) << 4)))));
              u16* dst = (lo < 0) ? pB : pA;
              dst[((size_t)(rgbase + row) * 128 + tprev) * 512 + q] = f2bf(m);
            }
          }
        }
      }
    }

    // ---- two passes over channel halves; gates = MFMA(h, W) + xq at update ----
#pragma unroll
    for (int p = 0; p < 2; ++p) {
      // xp loads issued at pass top; consumed after the K-loop (latency hidden)
      float xq[4][4];
#pragma unroll
      for (int g = 0; g < 4; ++g)
#pragma unroll
        for (int i = 0; i < 4; ++i) {
          int brow = (NR == 4) ? i : (lhi * 4 + i);
          xq[g][i] = xp[((size_t)(rgbase + brow) * 128 + t) * 1024 + g * 256 + p * 128 + w * 16 + llo];
        }

      f32x4 acc[MT][4];
#pragma unroll
      for (int mt = 0; mt < MT; ++mt)
#pragma unroll
        for (int g = 0; g < 4; ++g) acc[mt][g] = (f32x4){0.f, 0.f, 0.f, 0.f};

      short8 Wb3[3][4];   // 3-deep W pipeline (per gate tile)
      short8 afb[2][MT];  // 2-deep A pipeline
#pragma unroll
      for (int g = 0; g < 4; ++g) {
        size_t go = (size_t)(g * 256 + p * 128) * 512;
        Wb3[0][g] = *(const short8*)(Wl + go);
        Wb3[1][g] = *(const short8*)(Wl + go + 64);
      }
#pragma unroll
      for (int mt = 0; mt < MT; ++mt) {
        int vrow = mt * 16 + llo;
        afb[0][mt] = *(const short8*)((const char*)hb + vrow * 512 + SWZ(vrow, lhi * 16));
      }
#pragma unroll
      for (int ks = 0; ks < 8; ++ks) {
        if (ks < 6) {
#pragma unroll
          for (int g = 0; g < 4; ++g) {
            size_t go = (size_t)(g * 256 + p * 128) * 512;
            Wb3[(ks + 2) % 3][g] = *(const short8*)(Wl + go + (ks + 2) * 64);
          }
        }
        if (ks < 7) {
#pragma unroll
          for (int mt = 0; mt < MT; ++mt) {
            int vrow = mt * 16 + llo;
            afb[(ks + 1) & 1][mt] = *(const short8*)((const char*)hb + vrow * 512 + SWZ(vrow, (ks + 1) * 64 + lhi * 16));
          }
        }
#pragma unroll
        for (int g = 0; g < 4; ++g)
#pragma unroll
          for (int mt = 0; mt < MT; ++mt)
            acc[mt][g] = __builtin_amdgcn_mfma_f32_16x16x32_bf16(afb[ks & 1][mt], Wb3[ks % 3][g], acc[mt][g], 0, 0, 0);
      }

      // ---- cell update + h writes (to hw, the other buffer) ----
#pragma unroll
      for (int mt = 0; mt < MT; ++mt)
#pragma unroll
        for (int i = 0; i < 4; ++i) {
          int vrow = mt * 16 + lhi * 4 + i;
          int run = runbase + vrow / NR;
          bool act;
          if (PHASE == 2) act = true;
          else if (fwd)   act = (run <= 25) && (t >= run);
          else            act = (run == 0) || ((run <= 25) && (t <= run - 1));
          float ig = sigm(acc[mt][0][i] + xq[0][i]);
          float fg = sigm(acc[mt][1][i] + xq[1][i]);
          float gg = tanh_(acc[mt][2][i] + xq[2][i]);
          float og = sigm(acc[mt][3][i] + xq[3][i]);
          float c = fg * cst[p][mt][i] + ig * gg;
          c = act ? c : 0.f;
          cst[p][mt][i] = c;
          float h = act ? og * tanh_(c) : 0.f;
          u16 hbv = f2bf(h);
          int ch = p * 128 + w * 16 + llo;
          *(u16*)((char*)hw + ((vrow * 512 + ch * 2) ^ ((vrow & 7) << 4))) = hbv;
          if (PHASE == 2) {
            out[((size_t)(rgbase + vrow) * 128 + t) * 512 + ch] = hbv;
          } else if (grp == 0 && mt == 0 && lhi == 0) {  // full run (slot 0), rows = i
            out[((size_t)(rgbase + i) * 128 + t) * 256 + ch] = hbv;
          }
        }
    }

    __syncthreads();   // h(t) in hw complete; all reads of hb done
    cur ^= 1;
    tprev = t;
  }

  // epilogue: window-max of the final step (h in hlds[cur])
  if (PHASE == 1) {
    const u16* hb = hlds[cur];
#pragma unroll
    for (int rep = 0; rep < 2; ++rep) {
      int jj = tid + rep * 512;
      if (jj < 768) {
        int slot = jj / 48, rem = jj - slot * 48;
        int row = rem / 12, ws = rem - row * 12;
        int j = runbase + slot;
        if (j >= 1 && j <= 25 && (fwd ? (tprev >= j) : (tprev <= j - 1))) {
          int flatbase = (j - 1) * 512 + (fwd ? 0 : 256);
          int qlo = (flatbase * 5243) >> 17;
          int qhi = ((flatbase + 255) * 5243) >> 17;
          int q = qlo + ws;
          if (q <= qhi) {
            int lo = q * 25 - flatbase;
            int chlo = lo < 0 ? 0 : lo, chhi = lo + 24 > 255 ? 255 : lo + 24;
            int vrow = slot * NR + row;
            float m = -3.4e38f;
            for (int ch = chlo; ch <= chhi; ++ch)
              m = fmaxf(m, bf2f(*(const u16*)((const char*)hb + ((vrow * 512 + ch * 2) ^ ((vrow & 7) << 4)))));
            u16* dst = (lo < 0) ? pB : pA;
            dst[((size_t)(rgbase + row) * 128 + tprev) * 512 + q] = f2bf(m);
          }
        }
      }
    }
  }
}

// ---------- finish: NI = max(pA, pB, full-run slots) ----------
__global__ void finish_kernel(const u16* __restrict__ pA, const u16* __restrict__ pB,
                              const u16* __restrict__ HFfull, const u16* __restrict__ HBfull,
                              u16* __restrict__ NI) {
  const int bt = blockIdx.x;      // b*128 + t
  const int t = bt & 127;
  const int qidx = threadIdx.x;   // 0..511
  float m = fmaxf(bf2f(pA[(size_t)bt * 512 + qidx]), bf2f(pB[(size_t)bt * 512 + qidx]));
  const int base = qidx * 25;
#pragma unroll
  for (int r = 0; r < 25; ++r) {
    int idx = base + r;
    int k = idx >> 9;
    int c = idx & 511;
    if (c < 256) {
      if (t <= k) m = fmaxf(m, bf2f(HFfull[(size_t)bt * 256 + c]));
    } else {
      if (t > k) m = fmaxf(m, bf2f(HBfull[(size_t)bt * 256 + (c - 256)]));
    }
  }
  NI[(size_t)bt * 512 + qidx] = f2bf(m);
}

// ---------- host ----------
extern "C" void kernel_launch(void* const* d_in, const int* in_sizes, int n_in,
                              void* d_out, int out_size, void* d_ws, size_t ws_size,
                              hipStream_t stream) {
  (void)in_sizes; (void)n_in; (void)out_size; (void)ws_size;
  const float* input  = (const float*)d_in[0];
  const float* w_ih_f = (const float*)d_in[1];
  const float* w_hh_f = (const float*)d_in[2];
  const float* b_f    = (const float*)d_in[3];
  const float* w_ih_b = (const float*)d_in[4];
  const float* w_hh_b = (const float*)d_in[5];
  const float* b_b    = (const float*)d_in[6];
  const float* W_lin  = (const float*)d_in[7];
  const float* b_lin  = (const float*)d_in[8];

  char* ws = (char*)d_ws;
  size_t off = 0;
  auto alloc = [&](size_t bytes) {
    char* p = ws + off;
    off = (off + bytes + 255) & ~(size_t)255;
    return p;
  };
  // ~112 MiB total
  u16* WIH2  = (u16*)alloc(6291456);   // [2048,1536]: rows 0..1023 F, 1024..2047 B; [W_hi|W_hi|W_lo]
  u16* WHHF  = (u16*)alloc(524288);    // [1024,256]
  u16* WHHB  = (u16*)alloc(524288);
  u16* WLIN  = (u16*)alloc(524288);    // [512,512]
  float* XPF = (float*)alloc(33554432);  // [64,128,1024] f32 (reused stage-3)
  float* XPB = (float*)alloc(33554432);
  u16* NIbf  = (u16*)alloc(8388608);   // [8192,512] bf16
  u16* HFfull = (u16*)alloc(4194304);  // [8192,256] (REC aliases HFfull+HBfull later)
  u16* HBfull = (u16*)alloc(4194304);
  u16* XH    = (u16*)alloc(25165824);  // [8192,1536] = [x_hi|x_lo|x_hi]
  u16* pA    = XH;                     // [8192,512] bf16 partial-max A (aliases dead XH)
  u16* pB    = XH + 4194304;           // [8192,512] bf16 partial-max B
  u16* REC   = HFfull;                 // [8192,512] aliases HFfull+HBfull

  split_input_kernel<<<dim3(4096), dim3(256), 0, stream>>>(input, XH, 4194304);
  split_w_kernel<<<dim3(2048), dim3(256), 0, stream>>>(w_ih_f, WIH2);
  split_w_kernel<<<dim3(2048), dim3(256), 0, stream>>>(w_ih_b, WIH2 + (size_t)1024 * 1536);
  cvt_bf16_kernel<<<dim3(256), dim3(256), 0, stream>>>(w_hh_f, WHHF, 65536);
  cvt_bf16_kernel<<<dim3(256), dim3(256), 0, stream>>>(w_hh_b, WHHB, 65536);
  cvt_bf16_kernel<<<dim3(256), dim3(256), 0, stream>>>(W_lin, WLIN, 65536);

  // stage-1 xp (split precision), merged F+B: N=2048, K=1536
  gemm_bt_kernel<<<dim3(16, 64), dim3(256), 0, stream>>>(XH, 1536, WIH2, 1536,
      b_f, b_b, XPF, XPB, 1024, 8192, 1536);

  // init partial-max buffers to bf16 -inf (0xFF80) — XH dead now
  fill_u32_kernel<<<dim3(2048), dim3(256), 0, stream>>>((u32*)pA, 0xFF80FF80u, 4194304);

  // stage-1 scans: run-merged, 64 blocks
  scan_kernel<16, 4, 1><<<dim3(64), dim3(512), 0, stream>>>(WHHF, WHHB, XPF, XPB,
      HFfull, HBfull, pA, pB);

  // merge -> NI bf16
  finish_kernel<<<dim3(8192), dim3(512), 0, stream>>>(pA, pB, HFfull, HBfull, NIbf);

  // stage-3 xp, merged F+B: N=2048, K=512 (W_hi = first 512 cols of WIH2 rows)
  gemm_bt_kernel<<<dim3(16, 64), dim3(256), 0, stream>>>(NIbf, 512, WIH2, 1536,
      b_f, b_b, XPF, XPB, 1024, 8192, 512);

  // stage-3 bidirectional scan -> REC[bt][512]
  scan_kernel<1, 16, 2><<<dim3(8), dim3(512), 0, stream>>>(WHHF, WHHB, XPF, XPB,
      REC, REC + 256, pA, pB);

  // output = REC @ W_lin^T + b_lin
  gemm_bt_kernel<<<dim3(4, 64), dim3(256), 0, stream>>>(REC, 512, WLIN, 512,
      b_lin, b_lin, (float*)d_out, (float*)d_out, 512, 8192, 512);
}